// Round 9
// baseline (190.491 us; speedup 1.0000x reference)
//
#include <hip/hip_runtime.h>
#include <math.h>

#define A_TOT 8400
#define B_N   2
#define T_N   100
#define C_N   80
#define E_N   32
#define MH_N  64
#define MW_N  64
#define ROW_N 8363          // 4 + 80 + 85 + 4096 + 4098
#define NROWS (B_N*A_TOT)   // 16800
#define EPSF  1e-9f
#define PARAM_STRIDE 12
#define COMP_CAP 1536       // max positives per target row <=1189 (grid mask)
#define NEGINF -1e30f

// ---- kernel 0: hoist atan terms (per-bt and per-(b,a)) --------------------
__global__ __launch_bounds__(256) void k_prep(
    const float* __restrict__ pred_boxes, const float* __restrict__ target_bbox,
    float* __restrict__ pred_atan, float* __restrict__ tgt_atan) {
  int i = blockIdx.x * 256 + threadIdx.x;
  if (i < NROWS) {
    float4 pb = *(const float4*)(pred_boxes + (size_t)i*4);
    pred_atan[i] = atanf((pb.z - pb.x) / ((pb.w - pb.y) + EPSF));
  }
  if (i < B_N*T_N) {
    float4 g = *(const float4*)(target_bbox + i*4);
    tgt_atan[i] = atanf((g.z - g.x) / ((g.w - g.y) + EPSF));
  }
}

__device__ __forceinline__ float2 tmat_eval(
    float gx1, float gy1, float gx2, float gy2,
    float ax,  float ay,
    float px1, float py1, float px2, float py2,
    float cl, float atg, float atp) {
  float ix1 = fmaxf(gx1,px1), iy1 = fmaxf(gy1,py1);
  float ix2 = fminf(gx2,px2), iy2 = fminf(gy2,py2);
  float inter = fmaxf(ix2-ix1,0.f) * fmaxf(iy2-iy1,0.f);
  float wg = gx2-gx1, hg = gy2-gy1, wp = px2-px1, hp = py2-py1;
  float uni = wg*hg + wp*hp - inter + EPSF;
  float iou = inter / uni;
  float cw = fmaxf(gx2,px2) - fminf(gx1,px1);
  float ch = fmaxf(gy2,py2) - fminf(gy1,py1);
  float c2 = cw*cw + ch*ch + EPSF;
  float dx = gx1+gx2-px1-px2, dy = gy1+gy2-py1-py2;
  float rho2 = (dx*dx + dy*dy) * 0.25f;
  float da = atg - atp;
  float v  = 0.4052847345693511f * da * da;     // 4/pi^2
  float alpha = v / (1.f - iou + v + EPSF);
  float ciou = iou - rho2/c2 - alpha*v;
  float iouc = fminf(fmaxf(ciou, 0.f), 1.f);

  float tm = 0.f;
  if (ax > gx1 && ay > gy1 && ax < gx2 && ay < gy2) {   // strict grid mask
    float cp = 1.f / (1.f + expf(-cl));
    float i2 = iouc * iouc;
    tm = i2*i2*i2 * sqrtf(cp);                 // iou^6 * cls^0.5
  }
  return make_float2(tm, iouc);
}

// ---- kernel 1: per (b,t): row CIoU -> tmat; kth/maxt/maxiou ---------------
__global__ __launch_bounds__(512) void k_score(
    const float* __restrict__ cls_logits, const float* __restrict__ pred_boxes,
    const float* __restrict__ target_bbox, const int* __restrict__ target_cls,
    const float* __restrict__ anchors,
    const float* __restrict__ pred_atan, const float* __restrict__ tgt_atan,
    float* __restrict__ tmat,
    float* __restrict__ kth, float* __restrict__ maxt, float* __restrict__ maxiou) {
  int bt   = blockIdx.x;
  int b    = bt / T_N;
  int tid  = threadIdx.x;
  int lane = tid & 63, wid = tid >> 6;
  __shared__ float comp[COMP_CAP];
  __shared__ float redm[8], redi[8];
  __shared__ float wtop[8][10];
  __shared__ int   cnt;
  if (tid == 0) cnt = 0;
  __syncthreads();

  float4 g  = *(const float4*)(target_bbox + bt*4);
  int    tc = target_cls[bt];
  float atg = tgt_atan[bt];
  float* trow = tmat + (size_t)bt * A_TOT;

  float lm = 0.f, li = 0.f;
  for (int a = tid; a < A_TOT; a += 512) {
    float ax = anchors[a*2+0], ay = anchors[a*2+1];
    float4 pb = *(const float4*)(pred_boxes + ((size_t)(b*A_TOT+a))*4);
    float cl = cls_logits[((size_t)(b*A_TOT+a))*C_N + tc];
    float2 r = tmat_eval(g.x,g.y,g.z,g.w, ax,ay, pb.x,pb.y,pb.z,pb.w,
                         cl, atg, pred_atan[b*A_TOT + a]);
    trow[a] = r.x;
    li = fmaxf(li, r.y);
    if (r.x > 0.f) {
      lm = fmaxf(lm, r.x);
      comp[atomicAdd(&cnt, 1)] = r.x;
    }
  }
  #pragma unroll
  for (int off = 32; off; off >>= 1) {
    lm = fmaxf(lm, __shfl_xor(lm, off));
    li = fmaxf(li, __shfl_xor(li, off));
  }
  if (lane == 0) { redm[wid] = lm; redi[wid] = li; }
  __syncthreads();
  if (tid == 0) {
    float m = redm[0], mi = redi[0];
    #pragma unroll
    for (int w = 1; w < 8; w++) { m = fmaxf(m, redm[w]); mi = fmaxf(mi, redi[w]); }
    maxt[bt] = m; maxiou[bt] = mi;
  }
  int count = cnt;   // safe: after __syncthreads

  // per-wave top-10 over its strided slice of comp (<=3 elems/lane, in regs)
  int base = wid*64 + lane;
  float e0 = (base        < count) ? comp[base]        : NEGINF;
  float e1 = (base + 512  < count) ? comp[base + 512]  : NEGINF;
  float e2 = (base + 1024 < count) ? comp[base + 1024] : NEGINF;
  float mytop = NEGINF;
  #pragma unroll
  for (int k = 0; k < 10; k++) {
    float bv = e0; int bs = 0;
    if (e1 > bv) { bv = e1; bs = 1; }
    if (e2 > bv) { bv = e2; bs = 2; }
    float v = bv; int id = (lane << 2) | bs;
    #pragma unroll
    for (int off = 32; off; off >>= 1) {
      float ov = __shfl_xor(v, off); int oid = __shfl_xor(id, off);
      if (ov > v || (ov == v && oid < id)) { v = ov; id = oid; }
    }
    if ((id >> 2) == lane) {           // winner removes its element
      int s = id & 3;
      if (s == 0) e0 = NEGINF; else if (s == 1) e1 = NEGINF; else e2 = NEGINF;
    }
    if (lane == k) mytop = v;
  }
  if (lane < 10) wtop[wid][lane] = mytop;
  __syncthreads();

  if (wid == 0) {                      // merge 80 candidates in wave 0
    int ia = lane, ib = 64 + lane;
    float f0 = wtop[ia/10][ia%10];
    float f1 = (ib < 80) ? wtop[ib/10][ib%10] : NEGINF;
    float cur = NEGINF;
    #pragma unroll
    for (int k = 0; k < 10; k++) {
      float bv = f0; int bs = 0;
      if (f1 > bv) { bv = f1; bs = 1; }
      float v = bv; int id = (lane << 1) | bs;
      #pragma unroll
      for (int off = 32; off; off >>= 1) {
        float ov = __shfl_xor(v, off); int oid = __shfl_xor(id, off);
        if (ov > v || (ov == v && oid < id)) { v = ov; id = oid; }
      }
      if ((id >> 1) == lane) { if ((id & 1) == 0) f0 = NEGINF; else f1 = NEGINF; }
      cur = v;
    }
    if (lane == 0) kth[bt] = fmaxf(cur, 0.f);   // <10 positives -> 0 (ref zero-pad)
  }
}

// ---- kernel 2: per (b,a): assignment from stored tmat (bitwise-consistent)
__global__ __launch_bounds__(64) void k_assign(
    const float* __restrict__ tmat,
    const float* __restrict__ kth, const float* __restrict__ maxt, const float* __restrict__ maxiou,
    const float* __restrict__ target_bbox, const int* __restrict__ target_cls,
    const float* __restrict__ scalers,
    float* __restrict__ params) {
  int b   = blockIdx.y;
  int tid = threadIdx.x;
  int a   = blockIdx.x * 64 + tid;
  __shared__ float kths[T_N];
  for (int i = tid; i < T_N; i += 64) kths[i] = kth[b*T_N + i];
  __syncthreads();
  if (a >= A_TOT) return;

  const float* col = tmat + (size_t)b * T_N * A_TOT + a;
  float best = 0.f; int u = 0, any = 0;
  #pragma unroll 4
  for (int t = 0; t < T_N; t++) {
    float v = col[(size_t)t * A_TOT];
    if (v > 0.f && v >= kths[t]) {            // topk membership
      any = 1;
      if (v > best) { best = v; u = t; }      // argmax, first occurrence
    }
  }
  int bu = b*T_N + u;
  float ng = any ? best / (maxt[bu] + EPSF) * maxiou[bu] : 0.f;
  float4 tb = *(const float4*)(target_bbox + bu*4);
  float s = scalers[a];
  float area = (tb.z - tb.x) * (tb.w - tb.y) / (640.f*640.f);

  int row = b*A_TOT + a;
  float* pp = params + (size_t)row * PARAM_STRIDE;
  *(float4*)pp       = tb;
  *(float4*)(pp + 4) = make_float4(any ? 1.f : 0.f, ng, s, area);
  *(float4*)(pp + 8) = make_float4(__int_as_float(u), __int_as_float(target_cls[bu]), 0.f, 0.f);
}

// ---- kernel 3: sparse writer over memset-zeroed output --------------------
// one block per row; writes ~91 small fields always, seg data only if valid
__global__ __launch_bounds__(256) void k_sparse(
    const float* __restrict__ cls_logits, const float* __restrict__ pred_boxes,
    const float* __restrict__ mask_embs,  const float* __restrict__ protos,
    const float* __restrict__ t_masks,    const float* __restrict__ params,
    float* __restrict__ out) {
  unsigned row = blockIdx.x;
  int b   = row >= (unsigned)A_TOT;
  int tid = threadIdx.x;
  __shared__ float semb[E_N];

  const float* pp = params + (size_t)row * PARAM_STRIDE;
  float4 P0 = *(const float4*)pp;
  float4 P1 = *(const float4*)(pp + 4);
  int u  = __float_as_int(pp[8]);
  int ct = __float_as_int(pp[9]);
  bool valid = P1.x > 0.5f;
  size_t base = (size_t)row * ROW_N;

  // small fields
  if (tid < 92) {
    if (tid < 4) out[base + tid] = pred_boxes[(size_t)row*4 + tid] / P1.z;
    else if (tid < 84) out[base + tid] = cls_logits[(size_t)row*C_N + (tid-4)];
    else if (tid < 88) {
      float t = (tid==84)?P0.x:((tid==85)?P0.y:((tid==86)?P0.z:P0.w));
      out[base + tid] = t / P1.z;
    }
    else if (tid == 88) out[base + 88] = P1.x;
    else if (tid == 89) { if (valid) out[base + 89 + ct] = P1.y; }
    else if (tid == 90) out[base + 4265] = P1.w;
    else                out[base + 4266] = P1.x;
  }
  if (!valid) return;
  if (tid < E_N) semb[tid] = mask_embs[(size_t)row * E_N + tid];
  __syncthreads();

  float x1s = P0.x*0.1f, y1s = P0.y*0.1f, x2s = P0.z*0.1f, y2s = P0.w*0.1f;
  for (int p = tid; p < MH_N*MW_N; p += 256) {
    int h = p >> 6, w = p & 63;
    float fh = (float)h, fw = (float)w;
    if (fh >= y1s && fh < y2s && fw >= x1s && fw < x2s) {
      const float* pr = protos + ((size_t)((b*MH_N + h)*MW_N + w)) * E_N;
      float acc = 0.f;
      #pragma unroll
      for (int e = 0; e < E_N; e++) acc += semb[e] * pr[e];
      out[base + 169  + p] = 1.f / (1.f + expf(-acc));
      out[base + 4267 + p] = t_masks[((size_t)((b*MH_N + h)*MW_N + w)) * T_N + u];
    }
  }
}

extern "C" void kernel_launch(void* const* d_in, const int* in_sizes, int n_in,
                              void* d_out, int out_size, void* d_ws, size_t ws_size,
                              hipStream_t stream) {
  const float* cls_logits   = (const float*)d_in[0];
  const float* pred_boxes   = (const float*)d_in[1];
  const float* mask_embs    = (const float*)d_in[2];
  const float* protos       = (const float*)d_in[3];
  const int*   target_cls   = (const int*)  d_in[4];
  const float* target_bbox  = (const float*)d_in[5];
  const float* target_masks = (const float*)d_in[6];
  const float* anchors      = (const float*)d_in[7];
  const float* scalers      = (const float*)d_in[8];
  float* out = (float*)d_out;

  // ws layout (floats); ~7.6 MB total
  float* ws        = (float*)d_ws;
  float* kth       = ws;                               // 200
  float* maxt      = kth    + B_N*T_N;                 // 200
  float* maxiou    = maxt   + B_N*T_N;                 // 200
  float* params    = ws + 600;                         // 16800*12
  float* tmat      = params + (size_t)NROWS*PARAM_STRIDE;   // 1,680,000
  float* pred_atan = tmat + (size_t)B_N*T_N*A_TOT;     // 16800
  float* tgt_atan  = pred_atan + NROWS;                // 200

  hipMemsetAsync(out, 0, (size_t)NROWS * ROW_N * sizeof(float), stream);
  k_prep<<<(NROWS + 255)/256, 256, 0, stream>>>(pred_boxes, target_bbox,
                                                pred_atan, tgt_atan);
  k_score<<<B_N*T_N, 512, 0, stream>>>(cls_logits, pred_boxes, target_bbox,
                                       target_cls, anchors, pred_atan, tgt_atan,
                                       tmat, kth, maxt, maxiou);
  dim3 gAsn((A_TOT + 63)/64, B_N);                  // 132 x 2
  k_assign<<<gAsn, 64, 0, stream>>>(tmat, kth, maxt, maxiou, target_bbox,
                                    target_cls, scalers, params);
  k_sparse<<<NROWS, 256, 0, stream>>>(cls_logits, pred_boxes, mask_embs, protos,
                                      target_masks, params, out);
}

// Round 10
// 189.511 us; speedup vs baseline: 1.0052x; 1.0052x over previous
//
#include <hip/hip_runtime.h>
#include <math.h>

#define A_TOT 8400
#define B_N   2
#define T_N   100
#define C_N   80
#define E_N   32
#define MH_N  64
#define MW_N  64
#define ROW_N 8363          // 4 + 80 + 85 + 4096 + 4098
#define NROWS (B_N*A_TOT)   // 16800
#define EPSF  1e-9f
#define NCHUNK 4
#define CHUNK_A 2100        // 8400 / 4
#define COMP_CAP 1280       // positives per (bt,chunk) bounded by 1189 (grid mask)
#define NEGINF -1e30f

typedef float vfloat4 __attribute__((ext_vector_type(4)));

// ---- kernel 0: hoist atan terms (per-bt and per-(b,a)) --------------------
__global__ __launch_bounds__(256) void k_prep(
    const float* __restrict__ pred_boxes, const float* __restrict__ target_bbox,
    float* __restrict__ pred_atan, float* __restrict__ tgt_atan) {
  int i = blockIdx.x * 256 + threadIdx.x;
  if (i < NROWS) {
    float4 pb = *(const float4*)(pred_boxes + (size_t)i*4);
    pred_atan[i] = atanf((pb.z - pb.x) / ((pb.w - pb.y) + EPSF));
  }
  if (i < B_N*T_N) {
    float4 g = *(const float4*)(target_bbox + i*4);
    tgt_atan[i] = atanf((g.z - g.x) / ((g.w - g.y) + EPSF));
  }
}

__device__ __forceinline__ float2 tmat_eval(
    float gx1, float gy1, float gx2, float gy2,
    float ax,  float ay,
    float px1, float py1, float px2, float py2,
    float cl, float atg, float atp) {
  float ix1 = fmaxf(gx1,px1), iy1 = fmaxf(gy1,py1);
  float ix2 = fminf(gx2,px2), iy2 = fminf(gy2,py2);
  float inter = fmaxf(ix2-ix1,0.f) * fmaxf(iy2-iy1,0.f);
  float wg = gx2-gx1, hg = gy2-gy1, wp = px2-px1, hp = py2-py1;
  float uni = wg*hg + wp*hp - inter + EPSF;
  float iou = inter / uni;
  float cw = fmaxf(gx2,px2) - fminf(gx1,px1);
  float ch = fmaxf(gy2,py2) - fminf(gy1,py1);
  float c2 = cw*cw + ch*ch + EPSF;
  float dx = gx1+gx2-px1-px2, dy = gy1+gy2-py1-py2;
  float rho2 = (dx*dx + dy*dy) * 0.25f;
  float da = atg - atp;
  float v  = 0.4052847345693511f * da * da;     // 4/pi^2
  float alpha = v / (1.f - iou + v + EPSF);
  float ciou = iou - rho2/c2 - alpha*v;
  float iouc = fminf(fmaxf(ciou, 0.f), 1.f);

  float tm = 0.f;
  if (ax > gx1 && ay > gy1 && ax < gx2 && ay < gy2) {   // strict grid mask
    float cp = 1.f / (1.f + expf(-cl));
    float i2 = iouc * iouc;
    tm = i2*i2*i2 * sqrtf(cp);                 // iou^6 * cls^0.5
  }
  return make_float2(tm, iouc);
}

// ---- kernel 1: per (chunk, bt): tmat slice + partial top10/max ------------
__global__ __launch_bounds__(256) void k_score(
    const float* __restrict__ cls_logits, const float* __restrict__ pred_boxes,
    const float* __restrict__ target_bbox, const int* __restrict__ target_cls,
    const float* __restrict__ anchors,
    const float* __restrict__ pred_atan, const float* __restrict__ tgt_atan,
    float* __restrict__ tmat, float* __restrict__ top10s,
    float* __restrict__ pmaxt, float* __restrict__ pmaxi) {
  int chunk = blockIdx.x;
  int bt    = blockIdx.y;
  int b     = bt / T_N;
  int tid   = threadIdx.x;
  __shared__ float comp[COMP_CAP];
  __shared__ float red[256];
  __shared__ int   cnt, sidx;
  if (tid == 0) cnt = 0;
  __syncthreads();

  float4 g  = *(const float4*)(target_bbox + bt*4);
  int    tc = target_cls[bt];
  float atg = tgt_atan[bt];
  float* trow = tmat + (size_t)bt * A_TOT;

  int a0 = chunk * CHUNK_A;
  float lm = 0.f, li = 0.f;
  for (int a = a0 + tid; a < a0 + CHUNK_A; a += 256) {
    float ax = anchors[a*2+0], ay = anchors[a*2+1];
    float4 pb = *(const float4*)(pred_boxes + ((size_t)(b*A_TOT+a))*4);
    float cl = cls_logits[((size_t)(b*A_TOT+a))*C_N + tc];
    float2 r = tmat_eval(g.x,g.y,g.z,g.w, ax,ay, pb.x,pb.y,pb.z,pb.w,
                         cl, atg, pred_atan[b*A_TOT + a]);
    trow[a] = r.x;
    li = fmaxf(li, r.y);
    if (r.x > 0.f) {
      lm = fmaxf(lm, r.x);
      int i = atomicAdd(&cnt, 1);
      if (i < COMP_CAP) comp[i] = r.x;
    }
  }
  red[tid] = lm; __syncthreads();
  for (int s = 128; s > 0; s >>= 1) { if (tid < s) red[tid] = fmaxf(red[tid], red[tid+s]); __syncthreads(); }
  if (tid == 0) pmaxt[bt*NCHUNK + chunk] = red[0];
  __syncthreads();
  red[tid] = li; __syncthreads();
  for (int s = 128; s > 0; s >>= 1) { if (tid < s) red[tid] = fmaxf(red[tid], red[tid+s]); __syncthreads(); }
  if (tid == 0) pmaxi[bt*NCHUNK + chunk] = red[0];
  __syncthreads();
  int count = min(cnt, COMP_CAP);

  float* t10 = top10s + ((size_t)bt*NCHUNK + chunk) * 10;
  for (int k = 0; k < 10; k++) {
    float l = NEGINF;
    for (int i = tid; i < count; i += 256) l = fmaxf(l, comp[i]);
    red[tid] = l; __syncthreads();
    for (int s = 128; s > 0; s >>= 1) { if (tid < s) red[tid] = fmaxf(red[tid], red[tid+s]); __syncthreads(); }
    float m = red[0];
    if (tid == 0) sidx = 0x7fffffff;
    __syncthreads();
    if (m > NEGINF) {
      for (int i = tid; i < count; i += 256) if (comp[i] == m) atomicMin(&sidx, i);
    }
    __syncthreads();
    if (tid == 0) {
      if (sidx != 0x7fffffff) comp[sidx] = NEGINF;  // remove ONE instance
      t10[k] = m;
    }
    __syncthreads();
  }
}

// ---- kernel 2: per bt: merge 4x top-10 -> kth; finalize maxes -------------
__global__ __launch_bounds__(64) void k_merge(
    const float* __restrict__ top10s, const float* __restrict__ pmaxt,
    const float* __restrict__ pmaxi,
    float* __restrict__ kth, float* __restrict__ maxt, float* __restrict__ maxiou) {
  int bt = blockIdx.x;
  int lane = threadIdx.x;
  float cand = (lane < NCHUNK*10) ? top10s[(size_t)bt*NCHUNK*10 + lane] : NEGINF;
  float cur = NEGINF;
  #pragma unroll
  for (int k = 0; k < 10; k++) {
    float v = cand; int id = lane;
    #pragma unroll
    for (int off = 32; off; off >>= 1) {
      float ov = __shfl_xor(v, off); int oid = __shfl_xor(id, off);
      if (ov > v || (ov == v && oid < id)) { v = ov; id = oid; }
    }
    if (id == lane) cand = NEGINF;     // winner removes its instance
    cur = v;
  }
  float pm = (lane < NCHUNK) ? pmaxt[bt*NCHUNK + lane] : 0.f;
  float pi = (lane < NCHUNK) ? pmaxi[bt*NCHUNK + lane] : 0.f;
  #pragma unroll
  for (int off = 32; off; off >>= 1) {
    pm = fmaxf(pm, __shfl_xor(pm, off));
    pi = fmaxf(pi, __shfl_xor(pi, off));
  }
  if (lane == 0) {
    kth[bt]    = fmaxf(cur, 0.f);      // <10 positives -> 0 (ref zero-pad)
    maxt[bt]   = pm;
    maxiou[bt] = pi;
  }
}

// ---- kernel 3: per row: assign (from stored tmat) + write whole row -------
__global__ __launch_bounds__(256) void k_row(
    const float* __restrict__ cls_logits, const float* __restrict__ pred_boxes,
    const float* __restrict__ mask_embs,  const float* __restrict__ protos,
    const float* __restrict__ t_masks,    const float* __restrict__ tmat,
    const float* __restrict__ kth, const float* __restrict__ maxt,
    const float* __restrict__ maxiou, const float* __restrict__ target_bbox,
    const int* __restrict__ target_cls, const float* __restrict__ scalers,
    float* __restrict__ out) {
  unsigned row = blockIdx.x;
  int b   = row >= (unsigned)A_TOT;
  int a   = (int)row - b*A_TOT;
  int tid = threadIdx.x;
  __shared__ float sv[128];
  __shared__ int   st[128];
  __shared__ float semb[E_N];
  __shared__ float ctx[10];

  // phase 1: assignment (bitwise-consistent: stored tmat vs kth from same values)
  if (tid < 128) {
    float v = 0.f; int tt = 0x7fff;
    if (tid < T_N) {
      int bt = b*T_N + tid;
      float tv = tmat[(size_t)bt*A_TOT + a];
      if (tv > 0.f && tv >= kth[bt]) { v = tv; tt = tid; }
    }
    sv[tid] = v; st[tid] = tt;
  }
  if (tid < E_N) semb[tid] = mask_embs[(size_t)row*E_N + tid];
  __syncthreads();
  if (tid < 64) {
    float v1 = sv[tid];    int t1 = st[tid];
    float v2 = sv[tid+64]; int t2 = st[tid+64];
    if (v2 > v1 || (v2 == v1 && t2 < t1)) { v1 = v2; t1 = t2; }
    #pragma unroll
    for (int off = 32; off; off >>= 1) {
      float ov = __shfl_xor(v1, off); int ot = __shfl_xor(t1, off);
      if (ov > v1 || (ov == v1 && ot < t1)) { v1 = ov; t1 = ot; }
    }
    if (tid == 0) {
      int anyv = v1 > 0.f;
      int u = anyv ? t1 : 0;
      int bu = b*T_N + u;
      float4 tb = *(const float4*)(target_bbox + bu*4);
      float ng = anyv ? v1 / (maxt[bu] + EPSF) * maxiou[bu] : 0.f;
      ctx[0]=tb.x; ctx[1]=tb.y; ctx[2]=tb.z; ctx[3]=tb.w;
      ctx[4]= anyv ? 1.f : 0.f; ctx[5]=ng; ctx[6]=scalers[a];
      ctx[7]= (tb.z-tb.x)*(tb.w-tb.y)/(640.f*640.f);
      ctx[8]=__int_as_float(u); ctx[9]=__int_as_float(target_cls[bu]);
    }
  }
  __syncthreads();
  float tb0=ctx[0], tb1=ctx[1], tb2=ctx[2], tb3=ctx[3];
  float vld=ctx[4], ng=ctx[5], s=ctx[6], area=ctx[7];
  int   u  =__float_as_int(ctx[8]), ct=__float_as_int(ctx[9]);
  bool valid = vld > 0.5f;
  float x1s=tb0*0.1f, y1s=tb1*0.1f, x2s=tb2*0.1f, y2s=tb3*0.1f;
  size_t base = (size_t)row * ROW_N;

  auto val = [&](unsigned p) -> float {
    if (p < 84u) {
      if (p < 4u) return pred_boxes[(size_t)row*4 + p] / s;
      return cls_logits[(size_t)row*C_N + (p-4u)];
    }
    if (p < 169u) {
      if (p < 88u) { float t=(p==84u)?tb0:((p==85u)?tb1:((p==86u)?tb2:tb3)); return t/s; }
      if (p == 88u) return vld;
      return (valid && (int)p - 89 == ct) ? ng : 0.f;
    }
    if (p < 4265u) {                    // seg_pred
      if (!valid) return 0.f;
      unsigned q = p - 169u; int h = q >> 6, w = q & 63;
      float fh = (float)h, fw = (float)w;
      if (!(fh >= y1s && fh < y2s && fw >= x1s && fw < x2s)) return 0.f;
      const float* pr = protos + ((size_t)((b*MH_N + h)*MW_N + w)) * E_N;
      float acc = 0.f;
      #pragma unroll
      for (int e = 0; e < E_N; e++) acc += semb[e] * pr[e];
      return 1.f / (1.f + expf(-acc));
    }
    if (p == 4265u) return area;
    if (p == 4266u) return vld;
    if (!valid) return 0.f;             // align_seg
    unsigned q = p - 4267u; int h = q >> 6, w = q & 63;
    float fh = (float)h, fw = (float)w;
    if (!(fh >= y1s && fh < y2s && fw >= x1s && fw < x2s)) return 0.f;
    return t_masks[((size_t)((b*MH_N + h)*MW_N + w)) * T_N + u];
  };

  // phase 2: write entire row, 16B-aligned NT float4 body + scalar head/tail
  unsigned head = (4u - ((row * (unsigned)ROW_N) & 3u)) & 3u;
  if (tid < (int)head) out[base + tid] = val(tid);
  unsigned vec_end = head + (((unsigned)ROW_N - head) & ~3u);
  for (unsigned p = head + 4u*(unsigned)tid; p < vec_end; p += 1024u) {
    vfloat4 o;
    bool pure = (p >= 4267u) || (p >= 169u && p + 4u <= 4265u);
    if (pure && !valid) {
      o = (vfloat4)(0.f);
    } else {
      o.x = val(p); o.y = val(p+1u); o.z = val(p+2u); o.w = val(p+3u);
    }
    __builtin_nontemporal_store(o, (vfloat4*)(out + base + p));
  }
  unsigned tail_n = (unsigned)ROW_N - vec_end;     // 0..3
  if (tid >= 32 && tid < 32 + (int)tail_n)
    out[base + vec_end + (unsigned)(tid - 32)] = val(vec_end + (unsigned)(tid - 32));
}

extern "C" void kernel_launch(void* const* d_in, const int* in_sizes, int n_in,
                              void* d_out, int out_size, void* d_ws, size_t ws_size,
                              hipStream_t stream) {
  const float* cls_logits   = (const float*)d_in[0];
  const float* pred_boxes   = (const float*)d_in[1];
  const float* mask_embs    = (const float*)d_in[2];
  const float* protos       = (const float*)d_in[3];
  const int*   target_cls   = (const int*)  d_in[4];
  const float* target_bbox  = (const float*)d_in[5];
  const float* target_masks = (const float*)d_in[6];
  const float* anchors      = (const float*)d_in[7];
  const float* scalers      = (const float*)d_in[8];
  float* out = (float*)d_out;

  // ws layout (floats); ~6.8 MB total
  float* ws        = (float*)d_ws;
  float* tmat      = ws;                               // 1,680,000
  float* pred_atan = tmat + (size_t)B_N*T_N*A_TOT;     // 16,800
  float* tgt_atan  = pred_atan + NROWS;                // 200
  float* top10s    = tgt_atan + B_N*T_N;               // 8,000
  float* pmaxt     = top10s + (size_t)B_N*T_N*NCHUNK*10;  // 800
  float* pmaxi     = pmaxt + B_N*T_N*NCHUNK;           // 800
  float* kth       = pmaxi + B_N*T_N*NCHUNK;           // 200
  float* maxt      = kth + B_N*T_N;                    // 200
  float* maxiou    = maxt + B_N*T_N;                   // 200

  k_prep<<<(NROWS + 255)/256, 256, 0, stream>>>(pred_boxes, target_bbox,
                                                pred_atan, tgt_atan);
  dim3 gS(NCHUNK, B_N*T_N);
  k_score<<<gS, 256, 0, stream>>>(cls_logits, pred_boxes, target_bbox,
                                  target_cls, anchors, pred_atan, tgt_atan,
                                  tmat, top10s, pmaxt, pmaxi);
  k_merge<<<B_N*T_N, 64, 0, stream>>>(top10s, pmaxt, pmaxi, kth, maxt, maxiou);
  k_row<<<NROWS, 256, 0, stream>>>(cls_logits, pred_boxes, mask_embs, protos,
                                   target_masks, tmat, kth, maxt, maxiou,
                                   target_bbox, target_cls, scalers, out);
}

// Round 11
// 180.718 us; speedup vs baseline: 1.0541x; 1.0487x over previous
//
#include <hip/hip_runtime.h>
#include <math.h>

#define A_TOT 8400
#define B_N   2
#define T_N   100
#define C_N   80
#define E_N   32
#define MH_N  64
#define MW_N  64
#define ROW_N 8363          // 4 + 80 + 85 + 4096 + 4098
#define NROWS (B_N*A_TOT)   // 16800
#define EPSF  1e-9f
#define COMP_CAP 1536       // positives per bt bounded by 1189 (grid mask)
#define NEGINF -1e30f

typedef float vfloat4 __attribute__((ext_vector_type(4)));

__device__ __forceinline__ float2 tmat_eval(
    float gx1, float gy1, float gx2, float gy2,
    float ax,  float ay,
    float px1, float py1, float px2, float py2,
    float cl, float atg, float atp) {
  float ix1 = fmaxf(gx1,px1), iy1 = fmaxf(gy1,py1);
  float ix2 = fminf(gx2,px2), iy2 = fminf(gy2,py2);
  float inter = fmaxf(ix2-ix1,0.f) * fmaxf(iy2-iy1,0.f);
  float wg = gx2-gx1, hg = gy2-gy1, wp = px2-px1, hp = py2-py1;
  float uni = wg*hg + wp*hp - inter + EPSF;
  float iou = inter / uni;
  float cw = fmaxf(gx2,px2) - fminf(gx1,px1);
  float ch = fmaxf(gy2,py2) - fminf(gy1,py1);
  float c2 = cw*cw + ch*ch + EPSF;
  float dx = gx1+gx2-px1-px2, dy = gy1+gy2-py1-py2;
  float rho2 = (dx*dx + dy*dy) * 0.25f;
  float da = atg - atp;
  float v  = 0.4052847345693511f * da * da;     // 4/pi^2
  float alpha = v / (1.f - iou + v + EPSF);
  float ciou = iou - rho2/c2 - alpha*v;
  float iouc = fminf(fmaxf(ciou, 0.f), 1.f);

  float tm = 0.f;
  if (ax > gx1 && ay > gy1 && ax < gx2 && ay < gy2) {   // strict grid mask
    float cp = 1.f / (1.f + expf(-cl));
    float i2 = iouc * iouc;
    tm = i2*i2*i2 * sqrtf(cp);                 // iou^6 * cls^0.5
  }
  return make_float2(tm, iouc);
}

// ---- kernel 1: per bt: full row CIoU -> tmat; kth/maxt/maxiou in-block ----
__global__ __launch_bounds__(512) void k_score(
    const float* __restrict__ cls_logits, const float* __restrict__ pred_boxes,
    const float* __restrict__ target_bbox, const int* __restrict__ target_cls,
    const float* __restrict__ anchors,
    float* __restrict__ tmat,
    float* __restrict__ kth, float* __restrict__ maxt, float* __restrict__ maxiou) {
  int bt   = blockIdx.x;
  int b    = bt / T_N;
  int tid  = threadIdx.x;
  int lane = tid & 63, wid = tid >> 6;
  __shared__ float comp[COMP_CAP];
  __shared__ float redm[8], redi[8];
  __shared__ float wtop[8][10];
  __shared__ int   cnt;
  if (tid == 0) cnt = 0;
  __syncthreads();

  float4 g  = *(const float4*)(target_bbox + bt*4);
  int    tc = target_cls[bt];
  float atg = atanf((g.z - g.x) / ((g.w - g.y) + EPSF));
  float* trow = tmat + (size_t)bt * A_TOT;

  float lm = 0.f, li = 0.f;
  for (int a = tid; a < A_TOT; a += 512) {
    float ax = anchors[a*2+0], ay = anchors[a*2+1];
    float4 pb = *(const float4*)(pred_boxes + ((size_t)(b*A_TOT+a))*4);
    float cl = cls_logits[((size_t)(b*A_TOT+a))*C_N + tc];
    float atp = atanf((pb.z - pb.x) / ((pb.w - pb.y) + EPSF));
    float2 r = tmat_eval(g.x,g.y,g.z,g.w, ax,ay, pb.x,pb.y,pb.z,pb.w,
                         cl, atg, atp);
    trow[a] = r.x;
    li = fmaxf(li, r.y);
    if (r.x > 0.f) {
      lm = fmaxf(lm, r.x);
      comp[atomicAdd(&cnt, 1)] = r.x;
    }
  }
  #pragma unroll
  for (int off = 32; off; off >>= 1) {
    lm = fmaxf(lm, __shfl_xor(lm, off));
    li = fmaxf(li, __shfl_xor(li, off));
  }
  if (lane == 0) { redm[wid] = lm; redi[wid] = li; }
  __syncthreads();
  if (tid == 0) {
    float m = redm[0], mi = redi[0];
    #pragma unroll
    for (int w = 1; w < 8; w++) { m = fmaxf(m, redm[w]); mi = fmaxf(mi, redi[w]); }
    maxt[bt] = m; maxiou[bt] = mi;
  }
  int count = cnt;   // safe: after __syncthreads

  // per-wave top-10 over its strided slice of comp (<=3 elems/lane, in regs)
  int base = wid*64 + lane;
  float e0 = (base        < count) ? comp[base]        : NEGINF;
  float e1 = (base + 512  < count) ? comp[base + 512]  : NEGINF;
  float e2 = (base + 1024 < count) ? comp[base + 1024] : NEGINF;
  float mytop = NEGINF;
  #pragma unroll
  for (int k = 0; k < 10; k++) {
    float bv = e0; int bs = 0;
    if (e1 > bv) { bv = e1; bs = 1; }
    if (e2 > bv) { bv = e2; bs = 2; }
    float v = bv; int id = (lane << 2) | bs;
    #pragma unroll
    for (int off = 32; off; off >>= 1) {
      float ov = __shfl_xor(v, off); int oid = __shfl_xor(id, off);
      if (ov > v || (ov == v && oid < id)) { v = ov; id = oid; }
    }
    if ((id >> 2) == lane) {           // winner removes its element
      int s = id & 3;
      if (s == 0) e0 = NEGINF; else if (s == 1) e1 = NEGINF; else e2 = NEGINF;
    }
    if (lane == k) mytop = v;
  }
  if (lane < 10) wtop[wid][lane] = mytop;
  __syncthreads();

  if (wid == 0) {                      // merge 80 candidates in wave 0
    int ia = lane, ib = 64 + lane;
    float f0 = wtop[ia/10][ia%10];
    float f1 = (ib < 80) ? wtop[ib/10][ib%10] : NEGINF;
    float cur = NEGINF;
    #pragma unroll
    for (int k = 0; k < 10; k++) {
      float bv = f0; int bs = 0;
      if (f1 > bv) { bv = f1; bs = 1; }
      float v = bv; int id = (lane << 1) | bs;
      #pragma unroll
      for (int off = 32; off; off >>= 1) {
        float ov = __shfl_xor(v, off); int oid = __shfl_xor(id, off);
        if (ov > v || (ov == v && oid < id)) { v = ov; id = oid; }
      }
      if ((id >> 1) == lane) { if ((id & 1) == 0) f0 = NEGINF; else f1 = NEGINF; }
      cur = v;
    }
    if (lane == 0) kth[bt] = fmaxf(cur, 0.f);   // <10 positives -> 0 (ref zero-pad)
  }
}

// ---- kernel 2: per row: assign (from stored tmat) + write whole row -------
__global__ __launch_bounds__(256) void k_row(
    const float* __restrict__ cls_logits, const float* __restrict__ pred_boxes,
    const float* __restrict__ mask_embs,  const float* __restrict__ protos,
    const float* __restrict__ t_masks,    const float* __restrict__ tmat,
    const float* __restrict__ kth, const float* __restrict__ maxt,
    const float* __restrict__ maxiou, const float* __restrict__ target_bbox,
    const int* __restrict__ target_cls, const float* __restrict__ scalers,
    float* __restrict__ out) {
  unsigned row = blockIdx.x;
  int b   = row >= (unsigned)A_TOT;
  int a   = (int)row - b*A_TOT;
  int tid = threadIdx.x;
  __shared__ float sv[128];
  __shared__ int   st[128];
  __shared__ float semb[E_N];
  __shared__ float ctx[10];

  // phase 1: assignment (bitwise-consistent: stored tmat vs kth from same values)
  if (tid < 128) {
    float v = 0.f; int tt = 0x7fff;
    if (tid < T_N) {
      int bt = b*T_N + tid;
      float tv = tmat[(size_t)bt*A_TOT + a];
      if (tv > 0.f && tv >= kth[bt]) { v = tv; tt = tid; }
    }
    sv[tid] = v; st[tid] = tt;
  }
  if (tid < E_N) semb[tid] = mask_embs[(size_t)row*E_N + tid];
  __syncthreads();
  if (tid < 64) {
    float v1 = sv[tid];    int t1 = st[tid];
    float v2 = sv[tid+64]; int t2 = st[tid+64];
    if (v2 > v1 || (v2 == v1 && t2 < t1)) { v1 = v2; t1 = t2; }
    #pragma unroll
    for (int off = 32; off; off >>= 1) {
      float ov = __shfl_xor(v1, off); int ot = __shfl_xor(t1, off);
      if (ov > v1 || (ov == v1 && ot < t1)) { v1 = ov; t1 = ot; }
    }
    if (tid == 0) {
      int anyv = v1 > 0.f;
      int u = anyv ? t1 : 0;
      int bu = b*T_N + u;
      float4 tb = *(const float4*)(target_bbox + bu*4);
      float ng = anyv ? v1 / (maxt[bu] + EPSF) * maxiou[bu] : 0.f;
      ctx[0]=tb.x; ctx[1]=tb.y; ctx[2]=tb.z; ctx[3]=tb.w;
      ctx[4]= anyv ? 1.f : 0.f; ctx[5]=ng; ctx[6]=scalers[a];
      ctx[7]= (tb.z-tb.x)*(tb.w-tb.y)/(640.f*640.f);
      ctx[8]=__int_as_float(u); ctx[9]=__int_as_float(target_cls[bu]);
    }
  }
  __syncthreads();
  float tb0=ctx[0], tb1=ctx[1], tb2=ctx[2], tb3=ctx[3];
  float vld=ctx[4], ng=ctx[5], s=ctx[6], area=ctx[7];
  int   u  =__float_as_int(ctx[8]), ct=__float_as_int(ctx[9]);
  bool valid = vld > 0.5f;
  float x1s=tb0*0.1f, y1s=tb1*0.1f, x2s=tb2*0.1f, y2s=tb3*0.1f;
  size_t base = (size_t)row * ROW_N;

  auto val = [&](unsigned p) -> float {
    if (p < 84u) {
      if (p < 4u) return pred_boxes[(size_t)row*4 + p] / s;
      return cls_logits[(size_t)row*C_N + (p-4u)];
    }
    if (p < 169u) {
      if (p < 88u) { float t=(p==84u)?tb0:((p==85u)?tb1:((p==86u)?tb2:tb3)); return t/s; }
      if (p == 88u) return vld;
      return (valid && (int)p - 89 == ct) ? ng : 0.f;
    }
    if (p < 4265u) {                    // seg_pred
      if (!valid) return 0.f;
      unsigned q = p - 169u; int h = q >> 6, w = q & 63;
      float fh = (float)h, fw = (float)w;
      if (!(fh >= y1s && fh < y2s && fw >= x1s && fw < x2s)) return 0.f;
      const float* pr = protos + ((size_t)((b*MH_N + h)*MW_N + w)) * E_N;
      float acc = 0.f;
      #pragma unroll
      for (int e = 0; e < E_N; e++) acc += semb[e] * pr[e];
      return 1.f / (1.f + expf(-acc));
    }
    if (p == 4265u) return area;
    if (p == 4266u) return vld;
    if (!valid) return 0.f;             // align_seg
    unsigned q = p - 4267u; int h = q >> 6, w = q & 63;
    float fh = (float)h, fw = (float)w;
    if (!(fh >= y1s && fh < y2s && fw >= x1s && fw < x2s)) return 0.f;
    return t_masks[((size_t)((b*MH_N + h)*MW_N + w)) * T_N + u];
  };

  // phase 2: write entire row, 16B-aligned NT float4 body + scalar head/tail
  unsigned head = (4u - ((row * (unsigned)ROW_N) & 3u)) & 3u;
  if (tid < (int)head) out[base + tid] = val(tid);
  unsigned vec_end = head + (((unsigned)ROW_N - head) & ~3u);
  for (unsigned p = head + 4u*(unsigned)tid; p < vec_end; p += 1024u) {
    vfloat4 o;
    bool pure = (p >= 4267u) || (p >= 169u && p + 4u <= 4265u);
    if (pure && !valid) {
      o = (vfloat4)(0.f);
    } else {
      o.x = val(p); o.y = val(p+1u); o.z = val(p+2u); o.w = val(p+3u);
    }
    __builtin_nontemporal_store(o, (vfloat4*)(out + base + p));
  }
  unsigned tail_n = (unsigned)ROW_N - vec_end;     // 0..3
  if (tid >= 32 && tid < 32 + (int)tail_n)
    out[base + vec_end + (unsigned)(tid - 32)] = val(vec_end + (unsigned)(tid - 32));
}

extern "C" void kernel_launch(void* const* d_in, const int* in_sizes, int n_in,
                              void* d_out, int out_size, void* d_ws, size_t ws_size,
                              hipStream_t stream) {
  const float* cls_logits   = (const float*)d_in[0];
  const float* pred_boxes   = (const float*)d_in[1];
  const float* mask_embs    = (const float*)d_in[2];
  const float* protos       = (const float*)d_in[3];
  const int*   target_cls   = (const int*)  d_in[4];
  const float* target_bbox  = (const float*)d_in[5];
  const float* target_masks = (const float*)d_in[6];
  const float* anchors      = (const float*)d_in[7];
  const float* scalers      = (const float*)d_in[8];
  float* out = (float*)d_out;

  // ws layout (floats); ~6.7 MB total
  float* ws     = (float*)d_ws;
  float* tmat   = ws;                                  // 1,680,000
  float* kth    = tmat + (size_t)B_N*T_N*A_TOT;        // 200
  float* maxt   = kth + B_N*T_N;                       // 200
  float* maxiou = maxt + B_N*T_N;                      // 200

  k_score<<<B_N*T_N, 512, 0, stream>>>(cls_logits, pred_boxes, target_bbox,
                                       target_cls, anchors, tmat, kth, maxt, maxiou);
  k_row<<<NROWS, 256, 0, stream>>>(cls_logits, pred_boxes, mask_embs, protos,
                                   target_masks, tmat, kth, maxt, maxiou,
                                   target_bbox, target_cls, scalers, out);
}